// Round 12
// baseline (133.210 us; speedup 1.0000x reference)
//
#include <hip/hip_runtime.h>
#include <math.h>

// --- GF(2)-linear index helpers ---
// LDS bank swizzle: slot = i ^ ((i>>4)&15)  (involution)
__device__ __forceinline__ int sig(int i) { return i ^ ((i >> 4) & 15); }
// sig(finv(r)), r in [0,16): finv(c) = ((c ^ (c<<1)) & 0xFFF) ^ (bit11(c)*3)
__device__ __forceinline__ int gk(int r) {
    int j = (r ^ (r << 1)) & 0xFFF;
    return j ^ ((j >> 4) & 15);
}

// ---------- Kernel A: data-reupload params -> U3 matrices ----------
__global__ __attribute__((amdgpu_flat_work_group_size(256, 256)))
void qparam_kernel(const float* __restrict__ x, const float* __restrict__ rw,
                   const float* __restrict__ rb, float* __restrict__ uo, int total)
{
    const int g = blockIdx.x * 256 + threadIdx.x;   // g = b*12 + c
    if (g >= total) return;
    const int c = g % 12;
    const float4 xv = ((const float4*)x)[g];        // x viewed as [B,12,4]
    float prm[3];
    #pragma unroll
    for (int p = 0; p < 3; ++p) {
        const float4 wv = ((const float4*)rw)[c * 3 + p];
        prm[p] = rb[c * 3 + p] + wv.x * xv.x + wv.y * xv.y + wv.z * xv.z + wv.w * xv.w;
    }
    float st_, ct_; sincosf(0.5f * prm[0], &st_, &ct_);
    float sp_, cp_; sincosf(prm[1], &sp_, &cp_);
    float sl_, cl_; sincosf(prm[2], &sl_, &cl_);
    const float cpl = cp_ * cl_ - sp_ * sl_;
    const float spl = sp_ * cl_ + cp_ * sl_;
    // U3 row layout: {ct, 0, u01r, u01i, u10r, u10i, u11r, u11i}
    ((float4*)uo)[g * 2]     = make_float4(ct_, 0.0f, -cl_ * st_, -sl_ * st_);
    ((float4*)uo)[g * 2 + 1] = make_float4(cp_ * st_, sp_ * st_, cpl * ct_, spl * ct_);
}

// Apply 4 single-qubit gates (local bits 0..3) to a 16-amp register subcube.
// Coefficients in SGPRs (block-uniform loads). Scalar fmaf chains: sign
// structure folds into free VOP3 neg modifiers — no swap/shuffle ops.
__device__ __forceinline__ void apply4s(float2 v[16], const float* __restrict__ ub, int wbase) {
    #pragma unroll
    for (int g = 0; g < 4; ++g) {
        const float4 uA = ((const float4*)ub)[(wbase + g) * 2];
        const float4 uB = ((const float4*)ub)[(wbase + g) * 2 + 1];
        const float ct = uA.x, u01r = uA.z, u01i = uA.w;
        const float u10r = uB.x, u10i = uB.y, u11r = uB.z, u11i = uB.w;
        const int m = 1 << g;
        #pragma unroll
        for (int j = 0; j < 16; ++j) {
            if (j & m) continue;
            const float2 a0 = v[j], a1 = v[j | m];
            float2 n0, n1;
            n0.x = fmaf(ct, a0.x, fmaf(u01r, a1.x, -u01i * a1.y));
            n0.y = fmaf(ct, a0.y, fmaf(u01r, a1.y,  u01i * a1.x));
            n1.x = fmaf(u10r, a0.x, fmaf(-u10i, a0.y, fmaf(u11r, a1.x, -u11i * a1.y)));
            n1.y = fmaf(u10r, a0.y, fmaf( u10i, a0.x, fmaf(u11r, a1.y,  u11i * a1.x)));
            v[j]     = n0;
            v[j | m] = n1;
        }
    }
}

// ---------- Kernel B: TWO circuits per block ----------
// 64 KB LDS -> 2 blocks/CU; waves_per_eu(2,2) -> 256-VGPR budget (no spill).
// Each __syncthreads now covers two circuits' VALU work and total sequential
// blocks/CU halves (8 -> 4): barrier-drain residue ~halves.
__global__ __attribute__((amdgpu_flat_work_group_size(256, 256), amdgpu_waves_per_eu(2, 2)))
void qreup_kernel(const float* __restrict__ uin,  // [B,12,8] U3 matrices
                  const float* __restrict__ w1,   // [64,12]
                  const float* __restrict__ b1,   // [64]
                  const float* __restrict__ w2,   // [256,64]
                  const float* __restrict__ b2,   // [256]
                  float* __restrict__ out)        // [B,256]
{
    __shared__ float2 st[2][4096];                // 65536 B, swizzled layout sig(i)

    const int t = threadIdx.x;
    const int c0 = blockIdx.x * 2;                // circuits c0, c0+1
    const float* __restrict__ ubA = uin + c0 * 96;
    const float* __restrict__ ubB = ubA + 96;

    // slot bases (GF(2)-linear decompositions of the swizzled layout)
    const int base0 = (t << 4) | (t & 15);         // G0: slot = base0 ^ j
    const int base1 = ((t >> 4) << 8) | (t & 15);  // G1: slot = base1 ^ (17j)
    const int base2 = t ^ (t >> 4);                // G2: slot = base2 ^ (j<<8)
    const int a_ = t << 4;                         // gather base: sig(finv(t<<4))
    const int gj = ((a_ ^ (a_ << 1)) & 0xFFF) ^ ((a_ >> 11) * 3);
    const int gbase = gj ^ ((gj >> 4) & 15);

    // measurement accumulators (written in the L==2 tail)
    float ptA = 0.f, zAA = 0.f, z8A = 0.f, z9A = 0.f, z10A = 0.f;
    float ptB = 0.f, zAB = 0.f, z8B = 0.f, z9B = 0.f, z10B = 0.f;

    #pragma unroll 1
    for (int L = 0; L < 3; ++L) {
        float2 va[16], vb[16];
        // G0 (wires 0-3); previous layer's CNOT ring folded into the gather
        if (L == 0) {
            #pragma unroll
            for (int r = 0; r < 16; ++r) { va[r] = make_float2(0.f, 0.f); vb[r] = va[r]; }
            if (t == 0) { va[0].x = 1.0f; vb[0].x = 1.0f; }
        } else {
            #pragma unroll
            for (int r = 0; r < 16; ++r) { va[r] = st[0][gbase ^ gk(r)]; vb[r] = st[1][gbase ^ gk(r)]; }
        }
        apply4s(va, ubA, 0);
        apply4s(vb, ubB, 0);
        if (L) __syncthreads();   // anti-dep: all gathers done before overwrite
        #pragma unroll
        for (int r = 0; r < 16; ++r) { st[0][base0 ^ r] = va[r]; st[1][base0 ^ r] = vb[r]; }
        // G0 store -> G1 load is cluster-local (same wave); per-wave LDS ops
        // execute in order -> compiler fence suffices.
        __builtin_amdgcn_wave_barrier();
        #pragma unroll
        for (int r = 0; r < 16; ++r) { va[r] = st[0][base1 ^ (17 * r)]; vb[r] = st[1][base1 ^ (17 * r)]; }
        apply4s(va, ubA, 4);
        apply4s(vb, ubB, 4);
        #pragma unroll
        for (int r = 0; r < 16; ++r) { st[0][base1 ^ (17 * r)] = va[r]; st[1][base1 ^ (17 * r)] = vb[r]; }
        __syncthreads();          // G1 -> G2 is cross-wave
        #pragma unroll
        for (int r = 0; r < 16; ++r) { va[r] = st[0][base2 ^ (r << 8)]; vb[r] = st[1][base2 ^ (r << 8)]; }
        apply4s(va, ubA, 8);
        apply4s(vb, ubB, 8);
        if (L < 2) {
            #pragma unroll
            for (int r = 0; r < 16; ++r) { st[0][base2 ^ (r << 8)] = va[r]; st[1][base2 ^ (r << 8)] = vb[r]; }
            __syncthreads();      // G2 store -> next layer's gather
        } else {
            // Final CNOT ring + measurement folded into registers:
            // y = F(b): y_k = parity(b & (2^{k+1}-1)), y_0 = b_0 ^ parity(b).
            #pragma unroll
            for (int j = 0; j < 16; ++j) {
                const float prA = va[j].x * va[j].x + va[j].y * va[j].y;
                const float prB = vb[j].x * vb[j].x + vb[j].y * vb[j].y;
                const bool sP = __popc(j) & 1, s8 = j & 1;
                const bool s9 = __popc(j & 3) & 1, s10 = __popc(j & 7) & 1;
                ptA += prA;                      ptB += prB;
                zAA += sP  ? -prA : prA;         zAB += sP  ? -prB : prB;
                z8A += s8  ? -prA : prA;         z8B += s8  ? -prB : prB;
                z9A += s9  ? -prA : prA;         z9B += s9  ? -prB : prB;
                z10A += s10 ? -prA : prA;        z10B += s10 ? -prB : prB;
            }
        }
    }

    // zp[i] = per-thread signed probability sums (post-CNOT parities)
    const int par_t = __popc(t) & 1;
    float zpA[12], zpB[12];
    zpA[0] = ((t & 1) ^ par_t) ? -zAA : zAA;
    zpB[0] = ((t & 1) ^ par_t) ? -zAB : zAB;
    #pragma unroll
    for (int k = 1; k < 8; ++k) {
        const bool s = __popc(t & ((2 << k) - 1)) & 1;
        zpA[k] = s ? -ptA : ptA;
        zpB[k] = s ? -ptB : ptB;
    }
    zpA[8]  = par_t ? -z8A  : z8A;   zpB[8]  = par_t ? -z8B  : z8B;
    zpA[9]  = par_t ? -z9A  : z9A;   zpB[9]  = par_t ? -z9B  : z9B;
    zpA[10] = par_t ? -z10A : z10A;  zpB[10] = par_t ? -z10B : z10B;
    zpA[11] = par_t ? -zAA  : zAA;   zpB[11] = par_t ? -zAB  : zAB;

    #pragma unroll
    for (int i = 0; i < 12; ++i) {
        float a = zpA[i], b = zpB[i];
        #pragma unroll
        for (int off = 32; off > 0; off >>= 1) {
            a += __shfl_xor(a, off, 64);
            b += __shfl_xor(b, off, 64);
        }
        zpA[i] = a; zpB[i] = b;
    }

    // ---- epilogue arrays alias into st (all statevector reads are done)
    __syncthreads();
    float* stf = (float*)st;
    float* zredA = stf;          float* zredB = stf + 128;   // [4][12] each
    float* qzsA  = stf + 48;     float* qzsB  = stf + 176;   // [12]
    float* hbufA = stf + 64;     float* hbufB = stf + 192;   // [64]

    const int wave = t >> 6;
    if ((t & 63) == 0) {
        #pragma unroll
        for (int i = 0; i < 12; ++i) { zredA[wave * 12 + i] = zpA[i]; zredB[wave * 12 + i] = zpB[i]; }
    }
    __syncthreads();
    if (t < 12) {
        qzsA[t] = zredA[t] + zredA[12 + t] + zredA[24 + t] + zredA[36 + t];
        qzsB[t] = zredB[t] + zredB[12 + t] + zredB[24 + t] + zredB[36 + t];
    }
    __syncthreads();

    // ---- MLP head (both circuits; weights loaded once)
    if (t < 64) {
        float accA = b1[t], accB = b1[t];
        #pragma unroll
        for (int i = 0; i < 12; ++i) {
            const float w = w1[t * 12 + i];
            accA = fmaf(qzsA[i], w, accA);
            accB = fmaf(qzsB[i], w, accB);
        }
        hbufA[t] = fmaxf(accA, 0.0f);
        hbufB[t] = fmaxf(accB, 0.0f);
    }
    __syncthreads();
    float accA = b2[t], accB = b2[t];
    #pragma unroll 4   // cap outstanding float4 loads
    for (int k4 = 0; k4 < 16; ++k4) {
        const float4 wv = ((const float4*)w2)[t * 16 + k4];
        accA += wv.x * hbufA[k4 * 4 + 0] + wv.y * hbufA[k4 * 4 + 1]
              + wv.z * hbufA[k4 * 4 + 2] + wv.w * hbufA[k4 * 4 + 3];
        accB += wv.x * hbufB[k4 * 4 + 0] + wv.y * hbufB[k4 * 4 + 1]
              + wv.z * hbufB[k4 * 4 + 2] + wv.w * hbufB[k4 * 4 + 3];
    }
    out[c0 * 256 + t]       = accA;
    out[(c0 + 1) * 256 + t] = accB;
}

extern "C" void kernel_launch(void* const* d_in, const int* in_sizes, int n_in,
                              void* d_out, int out_size, void* d_ws, size_t ws_size,
                              hipStream_t stream) {
    const float* x  = (const float*)d_in[0];
    const float* rw = (const float*)d_in[1];
    const float* rb = (const float*)d_in[2];
    const float* w1 = (const float*)d_in[3];
    const float* b1 = (const float*)d_in[4];
    const float* w2 = (const float*)d_in[5];
    const float* b2 = (const float*)d_in[6];
    float* out = (float*)d_out;
    float* uws = (float*)d_ws;                    // [B*96] floats = 786432 B

    const int batch = in_sizes[0] / 48;           // x is [B,48]
    const int total = batch * 12;
    qparam_kernel<<<(total + 255) / 256, 256, 0, stream>>>(x, rw, rb, uws, total);
    qreup_kernel<<<batch / 2, 256, 0, stream>>>(uws, w1, b1, w2, b2, out);
}

// Round 14
// 124.436 us; speedup vs baseline: 1.0705x; 1.0705x over previous
//
#include <hip/hip_runtime.h>
#include <hip/hip_fp16.h>
#include <math.h>

// --- GF(2)-linear index helpers for the 4-byte-slot swizzle ---
// sigma2(i) = i ^ ((i>>4)&31): bijection on [0,4096); <=2-way (free) bank
// aliasing for all access patterns with 4-byte LDS slots.
// gk2(r) = sigma2(finv(r)), r in [0,16)
__device__ __forceinline__ int gk2(int r) {
    int j = (r ^ (r << 1)) & 0xFFF;
    return j ^ ((j >> 4) & 31);
}
// G2 slot offset: sigma2(r<<8) = (r<<8) ^ ((r&1)<<4)
__device__ __forceinline__ int g2k(int r) { return (r << 8) ^ ((r & 1) << 4); }

// ---------- Kernel A: data-reupload params -> U3 matrices ----------
__global__ __attribute__((amdgpu_flat_work_group_size(256, 256)))
void qparam_kernel(const float* __restrict__ x, const float* __restrict__ rw,
                   const float* __restrict__ rb, float* __restrict__ uo, int total)
{
    const int g = blockIdx.x * 256 + threadIdx.x;   // g = b*12 + c
    if (g >= total) return;
    const int c = g % 12;
    const float4 xv = ((const float4*)x)[g];        // x viewed as [B,12,4]
    float prm[3];
    #pragma unroll
    for (int p = 0; p < 3; ++p) {
        const float4 wv = ((const float4*)rw)[c * 3 + p];
        prm[p] = rb[c * 3 + p] + wv.x * xv.x + wv.y * xv.y + wv.z * xv.z + wv.w * xv.w;
    }
    float st_, ct_; sincosf(0.5f * prm[0], &st_, &ct_);
    float sp_, cp_; sincosf(prm[1], &sp_, &cp_);
    float sl_, cl_; sincosf(prm[2], &sl_, &cl_);
    const float cpl = cp_ * cl_ - sp_ * sl_;
    const float spl = sp_ * cl_ + cp_ * sl_;
    // U3 row layout: {ct, 0, u01r, u01i, u10r, u10i, u11r, u11i}
    ((float4*)uo)[g * 2]     = make_float4(ct_, 0.0f, -cl_ * st_, -sl_ * st_);
    ((float4*)uo)[g * 2 + 1] = make_float4(cp_ * st_, sp_ * st_, cpl * ct_, spl * ct_);
}

// Apply 4 single-qubit gates (local bits 0..3) to a 16-amp register subcube.
// Coefficients in SGPRs (block-uniform loads). Scalar fmaf chains: sign
// structure folds into free VOP3 neg modifiers — no swap/shuffle ops.
__device__ __forceinline__ void apply4s(float2 v[16], const float* __restrict__ ub, int wbase) {
    #pragma unroll
    for (int g = 0; g < 4; ++g) {
        const float4 uA = ((const float4*)ub)[(wbase + g) * 2];
        const float4 uB = ((const float4*)ub)[(wbase + g) * 2 + 1];
        const float ct = uA.x, u01r = uA.z, u01i = uA.w;
        const float u10r = uB.x, u10i = uB.y, u11r = uB.z, u11i = uB.w;
        const int m = 1 << g;
        #pragma unroll
        for (int j = 0; j < 16; ++j) {
            if (j & m) continue;
            const float2 a0 = v[j], a1 = v[j | m];
            float2 n0, n1;
            n0.x = fmaf(ct, a0.x, fmaf(u01r, a1.x, -u01i * a1.y));
            n0.y = fmaf(ct, a0.y, fmaf(u01r, a1.y,  u01i * a1.x));
            n1.x = fmaf(u10r, a0.x, fmaf(-u10i, a0.y, fmaf(u11r, a1.x, -u11i * a1.y)));
            n1.y = fmaf(u10r, a0.y, fmaf( u10i, a0.x, fmaf(u11r, a1.y,  u11i * a1.x)));
            v[j]     = n0;
            v[j | m] = n1;
        }
    }
}

__device__ __forceinline__ __half2 pack(float2 a) { return __float22half2_rn(a); }
__device__ __forceinline__ float2  unpk(__half2 h) { return __half22float2(h); }

// ---------- Kernel B: statevector sim + measurement + MLP head ----------
// fp16 LDS statevector (16384 B) -> 8 blocks/CU co-resident (wave-capped):
// every barrier drain overlaps other blocks' VALU work. Math stays fp32.
__global__ __attribute__((amdgpu_flat_work_group_size(256, 256), amdgpu_waves_per_eu(4, 8)))
void qreup_kernel(const float* __restrict__ uin,  // [B,12,8] U3 matrices
                  const float* __restrict__ w1,   // [64,12]
                  const float* __restrict__ b1,   // [64]
                  const float* __restrict__ w2,   // [256,64]
                  const float* __restrict__ b2,   // [256]
                  float* __restrict__ out)        // [B,256]
{
    __shared__ __half2 st[4096];                  // 16384 B, layout sigma2(i)

    const int t = threadIdx.x;
    const int b = blockIdx.x;
    const float* __restrict__ ub = uin + b * 96;  // block-uniform gate table

    // slot bases under sigma2 (all GF(2)-linear decompositions)
    const int base0 = (t << 4) ^ (t & 31);                                  // G0: slot = base0 ^ r
    const int base1 = ((t >> 4) << 8) | (((t >> 4) & 1) << 4) | (t & 15);   // G1: slot = base1 ^ (17r)
    const int base2 = t ^ (t >> 4);                                         // G2: slot = base2 ^ g2k(r)
    const int a_ = t << 4;                        // gather base: sigma2(finv(t<<4))
    const int gj = ((a_ ^ (a_ << 1)) & 0xFFF) ^ ((a_ >> 11) * 3);
    const int gbase = gj ^ ((gj >> 4) & 31);

    // measurement accumulators (written in the L==2 tail)
    float ptot = 0.f, zA = 0.f, z8 = 0.f, z9 = 0.f, z10 = 0.f;

    #pragma unroll 1
    for (int L = 0; L < 3; ++L) {
        float2 v[16];
        // G0 (wires 0-3); previous layer's CNOT ring folded into the gather
        if (L == 0) {
            #pragma unroll
            for (int r = 0; r < 16; ++r) v[r] = make_float2(0.0f, 0.0f);
            if (t == 0) v[0].x = 1.0f;
        } else {
            #pragma unroll
            for (int r = 0; r < 16; ++r) v[r] = unpk(st[gbase ^ gk2(r)]);
        }
        apply4s(v, ub, 0);
        if (L) __syncthreads();   // anti-dep: all gathers done before overwrite
        #pragma unroll
        for (int r = 0; r < 16; ++r) st[base0 ^ r] = pack(v[r]);
        // G0 store -> G1 load is cluster-local (same wave); per-wave LDS ops
        // execute in order -> compiler fence suffices.
        __builtin_amdgcn_wave_barrier();
        #pragma unroll
        for (int r = 0; r < 16; ++r) v[r] = unpk(st[base1 ^ (17 * r)]);
        apply4s(v, ub, 4);
        #pragma unroll
        for (int r = 0; r < 16; ++r) st[base1 ^ (17 * r)] = pack(v[r]);
        __syncthreads();          // G1 -> G2 is cross-wave
        #pragma unroll
        for (int r = 0; r < 16; ++r) v[r] = unpk(st[base2 ^ g2k(r)]);
        apply4s(v, ub, 8);
        if (L < 2) {
            #pragma unroll
            for (int r = 0; r < 16; ++r) st[base2 ^ g2k(r)] = pack(v[r]);
            __syncthreads();      // G2 store -> next layer's gather
        } else {
            // Final CNOT ring + measurement folded into registers:
            // y = F(b): y_k = parity(b & (2^{k+1}-1)), y_0 = b_0 ^ parity(b).
            // v[j] holds amp b = (j<<8)|t.
            #pragma unroll
            for (int j = 0; j < 16; ++j) {
                const float pr = v[j].x * v[j].x + v[j].y * v[j].y;
                ptot += pr;
                zA  += (__popc(j) & 1)     ? -pr : pr;
                z8  += (j & 1)             ? -pr : pr;
                z9  += (__popc(j & 3) & 1) ? -pr : pr;
                z10 += (__popc(j & 7) & 1) ? -pr : pr;
            }
        }
    }

    // zp[i] = per-thread signed probability sums (post-CNOT parities)
    const int par_t = __popc(t) & 1;
    float zp[12];
    zp[0] = ((t & 1) ^ par_t) ? -zA : zA;
    #pragma unroll
    for (int k = 1; k < 8; ++k)
        zp[k] = (__popc(t & ((2 << k) - 1)) & 1) ? -ptot : ptot;
    zp[8]  = par_t ? -z8  : z8;
    zp[9]  = par_t ? -z9  : z9;
    zp[10] = par_t ? -z10 : z10;
    zp[11] = par_t ? -zA  : zA;

    #pragma unroll
    for (int i = 0; i < 12; ++i) {
        float vv = zp[i];
        #pragma unroll
        for (int off = 32; off > 0; off >>= 1)
            vv += __shfl_xor(vv, off, 64);
        zp[i] = vv;
    }

    // ---- epilogue arrays alias into st (all statevector reads are done;
    // __syncthreads fences the half2->float reuse)
    __syncthreads();
    float* stf  = (float*)st;
    float* zred = stf;        // [4][12]
    float* qzs  = stf + 48;   // [12]
    float* hbuf = stf + 64;   // [64]

    const int wave = t >> 6;
    if ((t & 63) == 0) {
        #pragma unroll
        for (int i = 0; i < 12; ++i) zred[wave * 12 + i] = zp[i];
    }
    __syncthreads();
    if (t < 12)
        qzs[t] = zred[t] + zred[12 + t] + zred[24 + t] + zred[36 + t];
    __syncthreads();

    // ---- MLP head
    if (t < 64) {
        float acc = b1[t];
        #pragma unroll
        for (int i = 0; i < 12; ++i) acc += qzs[i] * w1[t * 12 + i];
        hbuf[t] = fmaxf(acc, 0.0f);
    }
    __syncthreads();
    float acc = b2[t];
    #pragma unroll 4   // cap outstanding float4 loads
    for (int k4 = 0; k4 < 16; ++k4) {
        const float4 wv = ((const float4*)w2)[t * 16 + k4];
        acc += wv.x * hbuf[k4 * 4 + 0] + wv.y * hbuf[k4 * 4 + 1]
             + wv.z * hbuf[k4 * 4 + 2] + wv.w * hbuf[k4 * 4 + 3];
    }
    out[b * 256 + t] = acc;
}

extern "C" void kernel_launch(void* const* d_in, const int* in_sizes, int n_in,
                              void* d_out, int out_size, void* d_ws, size_t ws_size,
                              hipStream_t stream) {
    const float* x  = (const float*)d_in[0];
    const float* rw = (const float*)d_in[1];
    const float* rb = (const float*)d_in[2];
    const float* w1 = (const float*)d_in[3];
    const float* b1 = (const float*)d_in[4];
    const float* w2 = (const float*)d_in[5];
    const float* b2 = (const float*)d_in[6];
    float* out = (float*)d_out;
    float* uws = (float*)d_ws;                    // [B*96] floats = 786432 B

    const int batch = in_sizes[0] / 48;           // x is [B,48]
    const int total = batch * 12;
    qparam_kernel<<<(total + 255) / 256, 256, 0, stream>>>(x, rw, rb, uws, total);
    qreup_kernel<<<batch, 256, 0, stream>>>(uws, w1, b1, w2, b2, out);
}

// Round 15
// 111.724 us; speedup vs baseline: 1.1923x; 1.1138x over previous
//
#include <hip/hip_runtime.h>
#include <hip/hip_fp16.h>
#include <math.h>

typedef _Float16 half8 __attribute__((ext_vector_type(8)));
typedef float f32x4 __attribute__((ext_vector_type(4)));

// Inverse of the CNOT-ring permutation (verified rounds 1-14)
__device__ __forceinline__ int finv12(int c) {
    return ((c ^ (c << 1)) & 0xFFF) ^ ((c >> 11) * 3);
}
// Per-group-layout bank swizzles on BYTE addresses (bits >=4 only, so 16B
// alignment of b128 ops is preserved). Applied identically on store and load
// of the same buffer generation -> correctness-neutral by construction.
__device__ __forceinline__ int sg0(int s) { return s ^ (((s >> 8) & 1) << 4) ^ (((s >> 9) & 1) << 6); }
__device__ __forceinline__ int sg1(int s) { return s ^ (((s >> 12) & 3) << 4) ^ (((s >> 7) & 1) << 6); }
__device__ __forceinline__ int sg2(int s) { return s ^ (((s >> 8) & 7) << 4); }

// ---------- Kernel A: data-reupload params -> U3 matrices (unchanged, verified) ----------
__global__ __attribute__((amdgpu_flat_work_group_size(256, 256)))
void qparam_kernel(const float* __restrict__ x, const float* __restrict__ rw,
                   const float* __restrict__ rb, float* __restrict__ uo, int total)
{
    const int g = blockIdx.x * 256 + threadIdx.x;   // g = b*12 + c
    if (g >= total) return;
    const int c = g % 12;
    const float4 xv = ((const float4*)x)[g];
    float prm[3];
    #pragma unroll
    for (int p = 0; p < 3; ++p) {
        const float4 wv = ((const float4*)rw)[c * 3 + p];
        prm[p] = rb[c * 3 + p] + wv.x * xv.x + wv.y * xv.y + wv.z * xv.z + wv.w * xv.w;
    }
    float st_, ct_; sincosf(0.5f * prm[0], &st_, &ct_);
    float sp_, cp_; sincosf(prm[1], &sp_, &cp_);
    float sl_, cl_; sincosf(prm[2], &sl_, &cl_);
    const float cpl = cp_ * cl_ - sp_ * sl_;
    const float spl = sp_ * cl_ + cp_ * sl_;
    // U3 row layout: {u00r,u00i, u01r,u01i, u10r,u10i, u11r,u11i}
    ((float4*)uo)[g * 2]     = make_float4(ct_, 0.0f, -cl_ * st_, -sl_ * st_);
    ((float4*)uo)[g * 2 + 1] = make_float4(cp_ * st_, sp_ * st_, cpl * ct_, spl * ct_);
}

// ---------- One MFMA group-pass ----------
// State layout in a buffer written by group G: slot(a,im) = n*32 + 2*m + im
// (f16 units), m = a[bits of G] (4b), n = remaining 8 bits ascending; byte
// addr swizzled by sgG. D = W @ S via mfma_f32_16x16x32_f16 with
// A[row=m'][k=2m+im] (A_re={Re,-Im}, A_im={Im,Re}; hi/lo split), B[k][col=n].
template<int G>
__device__ __forceinline__ void mfma_pass(
    const char* __restrict__ ldb, char* __restrict__ stb,
    half8 arh, half8 arl, half8 aih, half8 ail,
    int t, int l15, int q, int wv, bool first, bool last,
    float& A0, float& AT0, float& AT01, float& AR0, float& AR01)
{
    #pragma unroll
    for (int T = 0; T < 4; ++T) {
        const int tt = wv * 4 + T;
        half8 bfr;
        if (first) {                       // |0...0>: amp 0 only (G==0, L==0)
            half8 z = {};
            if (t == 0 && T == 0) z[0] = (_Float16)1.0f;
            bfr = z;
        } else {
            int raw4[4];
            #pragma unroll
            for (int j = 0; j < 4; ++j) {  // amp m = 4q+j; b32 = (re,im) pair
                int byte_;
                if (G == 0) {              // loads prev-layer G2 layout via CNOT
                    const int ap = finv12(j | (q << 2) | (l15 << 4) | (tt << 8));
                    byte_ = sg2(64 * (ap & 255) + 4 * ((ap >> 8) & 15));
                } else if (G == 1) {       // a = l15 | (4q+j)<<4 | tt<<8, layout g0
                    byte_ = sg0(256 * q + 64 * j + 1024 * tt + 4 * l15);
                } else {                   // a = l15 | tt<<4 | (4q+j)<<8, layout g1
                    byte_ = sg1(64 * l15 + 4096 * q + 1024 * j + 4 * tt);
                }
                raw4[j] = *(const int*)(ldb + byte_);
            }
            __builtin_memcpy(&bfr, raw4, 16);
        }
        f32x4 cre = {0.f, 0.f, 0.f, 0.f}, cim = {0.f, 0.f, 0.f, 0.f};
        cre = __builtin_amdgcn_mfma_f32_16x16x32_f16(arh, bfr, cre, 0, 0, 0);
        cre = __builtin_amdgcn_mfma_f32_16x16x32_f16(arl, bfr, cre, 0, 0, 0);
        cim = __builtin_amdgcn_mfma_f32_16x16x32_f16(aih, bfr, cim, 0, 0, 0);
        cim = __builtin_amdgcn_mfma_f32_16x16x32_f16(ail, bfr, cim, 0, 0, 0);
        if (!last) {
            // store own-layout: rows 4q+r, (re,im) interleaved -> one b128
            unsigned int ov4[4];
            #pragma unroll
            for (int r = 0; r < 4; ++r) {
                __half2 hp = __floats2half2_rn(cre[r], cim[r]);
                ov4[r] = *(unsigned int*)&hp;
            }
            int4 ov;
            __builtin_memcpy(&ov, ov4, 16);
            const int sb = 1024 * tt + 64 * l15 + 16 * q;
            const int sbyte = (G == 0) ? sg0(sb) : (G == 1) ? sg1(sb) : sg2(sb);
            *(int4*)(stb + sbyte) = ov;
        } else {
            // fold final CNOT + PauliZ measurement (parities of F(a)); amp
            // a = l15 | tt<<4 | (4q+r)<<8. Const sign parts over (T, r):
            const int sT0 = T & 1, sT01 = (T ^ (T >> 1)) & 1;
            #pragma unroll
            for (int r = 0; r < 4; ++r) {
                const float pr = cre[r] * cre[r] + cim[r] * cim[r];
                A0 += pr;
                AT0  += sT0 ? -pr : pr;
                AT01 += sT01 ? -pr : pr;
                AR0  += (sT01 ^ (r & 1)) ? -pr : pr;
                AR01 += (sT01 ^ ((r ^ (r >> 1)) & 1)) ? -pr : pr;
            }
        }
    }
}

// ---------- Kernel B: MFMA statevector sim + measurement + MLP head ----------
__global__ __attribute__((amdgpu_flat_work_group_size(256, 256), amdgpu_waves_per_eu(4, 4)))
void qreup_kernel(const float* __restrict__ uin,  // [B,12,8] U3 matrices
                  const float* __restrict__ w1, const float* __restrict__ b1,
                  const float* __restrict__ w2, const float* __restrict__ b2,
                  float* __restrict__ out)
{
    __shared__ __align__(16) char lds[38912];     // 2x16KB state dbuf + 6KB W
    char* const buf0 = lds;
    char* const buf1 = lds + 16384;
    char* const wl   = lds + 32768;

    const int t = threadIdx.x;
    const int b = blockIdx.x;
    const float* __restrict__ ub = uin + b * 96;
    const int l15 = t & 15, q = (t >> 4) & 3, wv = t >> 6;

    // ---- Build W_g = tensor product of 4 U3s; store hi/lo f16 planes,
    //      (re,im) interleaved: plane[g][hilo][row=m'][2m+im]
    {
        const int mp = t >> 4, mm = t & 15;
        #pragma unroll
        for (int g = 0; g < 3; ++g) {
            const float* p0 = ub + g * 32 + ((mp & 1) * 4 + (mm & 1) * 2);
            float wr = p0[0], wi = p0[1];
            #pragma unroll
            for (int bq = 1; bq < 4; ++bq) {
                const float* p = ub + g * 32 + bq * 8 + ((mp >> bq) & 1) * 4 + ((mm >> bq) & 1) * 2;
                const float br = p[0], bi = p[1];
                const float nr = wr * br - wi * bi, ni = wr * bi + wi * br;
                wr = nr; wi = ni;
            }
            const _Float16 hr = (_Float16)wr, hi_ = (_Float16)wi;
            const _Float16 lr = (_Float16)(wr - (float)hr), li = (_Float16)(wi - (float)hi_);
            union { _Float16 h[2]; unsigned int u; } ph, pl_;
            ph.h[0] = hr;  ph.h[1] = hi_;
            pl_.h[0] = lr; pl_.h[1] = li;
            *(unsigned int*)(wl + g * 2048 +        mp * 64 + mm * 4) = ph.u;
            *(unsigned int*)(wl + g * 2048 + 1024 + mp * 64 + mm * 4) = pl_.u;
        }
    }
    __syncthreads();

    // ---- A-fragments (A[row=lane&15][k=8*quad+j]): re-variant = {Re,-Im}
    //      (negate high f16 of each pair), im-variant = {Im,Re} (swap halves)
    half8 ArH[3], ArL[3], AiH[3], AiL[3];
    #pragma unroll
    for (int g = 0; g < 3; ++g) {
        #pragma unroll
        for (int hl = 0; hl < 2; ++hl) {
            int4 raw = *(const int4*)(wl + g * 2048 + hl * 1024 + l15 * 64 + q * 16);
            int re4[4], im4[4];
            int rr[4] = {raw.x, raw.y, raw.z, raw.w};
            #pragma unroll
            for (int i = 0; i < 4; ++i) {
                re4[i] = rr[i] ^ 0x80000000;
                im4[i] = (int)(((unsigned)rr[i] >> 16) | ((unsigned)rr[i] << 16));
            }
            half8 hre, him;
            __builtin_memcpy(&hre, re4, 16);
            __builtin_memcpy(&him, im4, 16);
            if (hl == 0) { ArH[g] = hre; AiH[g] = him; }
            else         { ArL[g] = hre; AiL[g] = him; }
        }
    }

    // ---- 3 layers x 3 group-passes, double-buffered
    float A0 = 0.f, AT0 = 0.f, AT01 = 0.f, AR0 = 0.f, AR01 = 0.f;
    #pragma unroll 1
    for (int L = 0; L < 3; ++L) {
        char* const bA = (L & 1) ? buf1 : buf0;   // G0/G2 store here
        char* const bB = (L & 1) ? buf0 : buf1;   // G1 stores here
        if (L) __syncthreads();
        mfma_pass<0>(bB, bA, ArH[0], ArL[0], AiH[0], AiL[0], t, l15, q, wv,
                     L == 0, false, A0, AT0, AT01, AR0, AR01);
        __syncthreads();
        mfma_pass<1>(bA, bB, ArH[1], ArL[1], AiH[1], AiL[1], t, l15, q, wv,
                     false, false, A0, AT0, AT01, AR0, AR01);
        __syncthreads();
        mfma_pass<2>(bB, bA, ArH[2], ArL[2], AiH[2], AiL[2], t, l15, q, wv,
                     false, L == 2, A0, AT0, AT01, AR0, AR01);
    }

    // ---- per-thread signed sums -> zp[12] (post-CNOT parities)
    const int pl = __popc(l15) & 1;
    const int wv0 = wv & 1, wv1 = (wv >> 1) & 1, wv01 = wv0 ^ wv1;
    const int q0 = q & 1, q1 = (q >> 1) & 1;
    float zp[12];
    zp[1] = (__popc(l15 & 3) & 1) ? -A0 : A0;
    zp[2] = (__popc(l15 & 7) & 1) ? -A0 : A0;
    zp[3] = pl ? -A0 : A0;
    zp[4] = pl ? -AT0 : AT0;
    zp[5] = pl ? -AT01 : AT01;
    zp[6] = (pl ^ wv0) ? -AT01 : AT01;
    zp[7] = (pl ^ wv0 ^ wv1) ? -AT01 : AT01;
    zp[8] = (pl ^ wv01) ? -AR0 : AR0;
    zp[9] = (pl ^ wv01) ? -AR01 : AR01;
    zp[10] = (pl ^ wv01 ^ q0) ? -AR01 : AR01;
    zp[11] = (pl ^ wv01 ^ q0 ^ q1) ? -AR01 : AR01;
    zp[0]  = ((l15 & 1) ^ pl ^ wv01 ^ q0 ^ q1) ? -AR01 : AR01;

    #pragma unroll
    for (int i = 0; i < 12; ++i) {
        float vv = zp[i];
        #pragma unroll
        for (int off = 32; off > 0; off >>= 1)
            vv += __shfl_xor(vv, off, 64);
        zp[i] = vv;
    }

    // ---- epilogue (r11-verified), aliasing LDS
    __syncthreads();
    float* stf  = (float*)lds;
    float* zred = stf;        // [4][12]
    float* qzs  = stf + 48;   // [12]
    float* hbuf = stf + 64;   // [64]

    if ((t & 63) == 0) {
        #pragma unroll
        for (int i = 0; i < 12; ++i) zred[wv * 12 + i] = zp[i];
    }
    __syncthreads();
    if (t < 12)
        qzs[t] = zred[t] + zred[12 + t] + zred[24 + t] + zred[36 + t];
    __syncthreads();

    if (t < 64) {
        float acc = b1[t];
        #pragma unroll
        for (int i = 0; i < 12; ++i) acc += qzs[i] * w1[t * 12 + i];
        hbuf[t] = fmaxf(acc, 0.0f);
    }
    __syncthreads();
    float acc = b2[t];
    #pragma unroll 4
    for (int k4 = 0; k4 < 16; ++k4) {
        const float4 wvv = ((const float4*)w2)[t * 16 + k4];
        acc += wvv.x * hbuf[k4 * 4 + 0] + wvv.y * hbuf[k4 * 4 + 1]
             + wvv.z * hbuf[k4 * 4 + 2] + wvv.w * hbuf[k4 * 4 + 3];
    }
    out[b * 256 + t] = acc;
}

extern "C" void kernel_launch(void* const* d_in, const int* in_sizes, int n_in,
                              void* d_out, int out_size, void* d_ws, size_t ws_size,
                              hipStream_t stream) {
    const float* x  = (const float*)d_in[0];
    const float* rw = (const float*)d_in[1];
    const float* rb = (const float*)d_in[2];
    const float* w1 = (const float*)d_in[3];
    const float* b1 = (const float*)d_in[4];
    const float* w2 = (const float*)d_in[5];
    const float* b2 = (const float*)d_in[6];
    float* out = (float*)d_out;
    float* uws = (float*)d_ws;                    // [B*96] floats = 786432 B

    const int batch = in_sizes[0] / 48;           // x is [B,48]
    const int total = batch * 12;
    qparam_kernel<<<(total + 255) / 256, 256, 0, stream>>>(x, rw, rb, uws, total);
    qreup_kernel<<<batch, 256, 0, stream>>>(uws, w1, b1, w2, b2, out);
}

// Round 16
// 100.243 us; speedup vs baseline: 1.3289x; 1.1145x over previous
//
#include <hip/hip_runtime.h>
#include <hip/hip_fp16.h>
#include <math.h>

typedef _Float16 half8 __attribute__((ext_vector_type(8)));
typedef float f32x4 __attribute__((ext_vector_type(4)));

// prefix-parity nibble: bit k = parity of bits 0..k of 4-bit x
__device__ __forceinline__ int pfx4(int x) {
    return (x ^ (x << 1) ^ (x << 2) ^ (x << 3)) & 15;
}

// ---------- Kernel A: data-reupload params -> U3 matrices (verified) ----------
__global__ __attribute__((amdgpu_flat_work_group_size(256, 256)))
void qparam_kernel(const float* __restrict__ x, const float* __restrict__ rw,
                   const float* __restrict__ rb, float* __restrict__ uo, int total)
{
    const int g = blockIdx.x * 256 + threadIdx.x;   // g = b*12 + c
    if (g >= total) return;
    const int c = g % 12;
    const float4 xv = ((const float4*)x)[g];
    float prm[3];
    #pragma unroll
    for (int p = 0; p < 3; ++p) {
        const float4 wv = ((const float4*)rw)[c * 3 + p];
        prm[p] = rb[c * 3 + p] + wv.x * xv.x + wv.y * xv.y + wv.z * xv.z + wv.w * xv.w;
    }
    float st_, ct_; sincosf(0.5f * prm[0], &st_, &ct_);
    float sp_, cp_; sincosf(prm[1], &sp_, &cp_);
    float sl_, cl_; sincosf(prm[2], &sl_, &cl_);
    const float cpl = cp_ * cl_ - sp_ * sl_;
    const float spl = sp_ * cl_ + cp_ * sl_;
    ((float4*)uo)[g * 2]     = make_float4(ct_, 0.0f, -cl_ * st_, -sl_ * st_);
    ((float4*)uo)[g * 2 + 1] = make_float4(cp_ * st_, sp_ * st_, cpl * ct_, spl * ct_);
}

// ---------- Kernel B: MFMA statevector sim, conflict-free LDS layouts ----------
__global__ __attribute__((amdgpu_flat_work_group_size(256, 256), amdgpu_waves_per_eu(4, 4)))
void qreup_kernel(const float* __restrict__ uin,  // [B,12,8] U3 matrices
                  const float* __restrict__ w1, const float* __restrict__ b1,
                  const float* __restrict__ w2, const float* __restrict__ b2,
                  float* __restrict__ out)
{
    __shared__ __align__(16) char lds[32768];     // 2 x 16KB rotating buffers
    char* const wl = lds;                         // W planes (dead after A-frag load)

    const int t = threadIdx.x;
    const int b = blockIdx.x;
    const float* __restrict__ ub = uin + b * 96;
    const int l15 = t & 15, q = (t >> 4) & 3, wv = t >> 6;

    // ---- Build W_g = tensor product of 4 U3s; hi/lo f16 planes (r15-verified)
    {
        const int mp = t >> 4, mm = t & 15;
        #pragma unroll
        for (int g = 0; g < 3; ++g) {
            const float* p0 = ub + g * 32 + ((mp & 1) * 4 + (mm & 1) * 2);
            float wr = p0[0], wi = p0[1];
            #pragma unroll
            for (int bq = 1; bq < 4; ++bq) {
                const float* p = ub + g * 32 + bq * 8 + ((mp >> bq) & 1) * 4 + ((mm >> bq) & 1) * 2;
                const float br = p[0], bi = p[1];
                const float nr = wr * br - wi * bi, ni = wr * bi + wi * br;
                wr = nr; wi = ni;
            }
            const _Float16 hr = (_Float16)wr, hi_ = (_Float16)wi;
            const _Float16 lr = (_Float16)(wr - (float)hr), li = (_Float16)(wi - (float)hi_);
            union { _Float16 h[2]; unsigned int u; } ph, pl_;
            ph.h[0] = hr;  ph.h[1] = hi_;
            pl_.h[0] = lr; pl_.h[1] = li;
            *(unsigned int*)(wl + g * 2048 +        mp * 64 + mm * 4) = ph.u;
            *(unsigned int*)(wl + g * 2048 + 1024 + mp * 64 + mm * 4) = pl_.u;
        }
    }
    __syncthreads();

    // ---- A-fragments (r15-verified): re={Re,-Im}, im={Im,Re}, hi/lo split
    half8 ArH[3], ArL[3], AiH[3], AiL[3];
    #pragma unroll
    for (int g = 0; g < 3; ++g) {
        #pragma unroll
        for (int hl = 0; hl < 2; ++hl) {
            int4 raw = *(const int4*)(wl + g * 2048 + hl * 1024 + l15 * 64 + q * 16);
            int re4[4], im4[4];
            int rr[4] = {raw.x, raw.y, raw.z, raw.w};
            #pragma unroll
            for (int i = 0; i < 4; ++i) {
                re4[i] = rr[i] ^ 0x80000000;
                im4[i] = (int)(((unsigned)rr[i] >> 16) | ((unsigned)rr[i] << 16));
            }
            half8 hre, him;
            __builtin_memcpy(&hre, re4, 16);
            __builtin_memcpy(&him, im4, 16);
            if (hl == 0) { ArH[g] = hre; AiH[g] = him; }
            else         { ArL[g] = hre; AiL[g] = him; }
        }
    }

    const int Ml = pfx4(l15);            // B0-store M nibble (prefix parities of l15)
    const int piL = (Ml >> 3) & 1;       // parity(l15)

    float A0 = 0.f, AT0 = 0.f, AT01 = 0.f, AR0 = 0.f, AR01 = 0.f;
    char* rbuf = lds;                    // pass p reads buf[p&1]
    char* wbuf = lds + 16384;

    #pragma unroll 1
    for (int L = 0; L < 3; ++L) {
        // ================= pass G0 =================
        if (L) __syncthreads();
        #pragma unroll
        for (int T = 0; T < 4; ++T) {
            const int tt = wv * 4 + T;
            half8 bfr;
            if (L == 0) {
                half8 z = {};
                if (t == 0 && T == 0) z[0] = (_Float16)1.0f;
                bfr = z;
            } else {
                // B0 load (CNOT folded via prefix-parity layout); nu = 16tt+l15
                const int nu = 16 * tt + l15;
                const int al = ((l15 >> 1) & 1) | ((((l15 >> 1) ^ (l15 >> 2)) & 1) << 1);
                const int be = ((tt >> 1) ^ (tt >> 2)) & 1;
                int4 raw = *(const int4*)(rbuf + 64 * (nu ^ be) + 16 * (q ^ al));
                if (tt & 8) {            // wave-uniform within-block pair swap
                    int tmp = raw.x; raw.x = raw.y; raw.y = tmp;
                    tmp = raw.z; raw.z = raw.w; raw.w = tmp;
                }
                __builtin_memcpy(&bfr, &raw, 16);
            }
            f32x4 cre = {0.f,0.f,0.f,0.f}, cim = {0.f,0.f,0.f,0.f};
            cre = __builtin_amdgcn_mfma_f32_16x16x32_f16(ArH[0], bfr, cre, 0, 0, 0);
            cre = __builtin_amdgcn_mfma_f32_16x16x32_f16(ArL[0], bfr, cre, 0, 0, 0);
            cim = __builtin_amdgcn_mfma_f32_16x16x32_f16(AiH[0], bfr, cim, 0, 0, 0);
            cim = __builtin_amdgcn_mfma_f32_16x16x32_f16(AiL[0], bfr, cim, 0, 0, 0);
            // B1 scatter-store: amp a[0:4)=4q+r, a[4:8)=l15, a[8:12)=tt
            const int als = q ^ ((tt >> 1) & 3);
            const int bes = (tt ^ q) & 1;
            const int D = 4 * (l15 ^ (als << 2));
            #pragma unroll
            for (int r = 0; r < 4; ++r) {
                const int nu = (4 * q + r) + 16 * tt;
                __half2 hp = __floats2half2_rn(cre[r], cim[r]);
                *(unsigned int*)(wbuf + 64 * (nu ^ bes) + D) = *(unsigned int*)&hp;
            }
        }
        { char* tmp = rbuf; rbuf = wbuf; wbuf = tmp; }

        // ================= pass G1 =================
        __syncthreads();
        #pragma unroll
        for (int T = 0; T < 4; ++T) {
            const int tt = wv * 4 + T;
            // B1 load: nu = tt + 16*l15 (lane split l15=a[8:12), tt=a[0:4))
            const int nu = tt + 16 * l15;
            const int al = ((tt >> 2) & 3) ^ ((l15 >> 1) & 3);
            const int be = (l15 ^ (tt >> 2)) & 1;
            int4 raw = *(const int4*)(rbuf + 64 * (nu ^ be) + 16 * (q ^ al));
            half8 bfr; __builtin_memcpy(&bfr, &raw, 16);
            f32x4 cre = {0.f,0.f,0.f,0.f}, cim = {0.f,0.f,0.f,0.f};
            cre = __builtin_amdgcn_mfma_f32_16x16x32_f16(ArH[1], bfr, cre, 0, 0, 0);
            cre = __builtin_amdgcn_mfma_f32_16x16x32_f16(ArL[1], bfr, cre, 0, 0, 0);
            cim = __builtin_amdgcn_mfma_f32_16x16x32_f16(AiH[1], bfr, cim, 0, 0, 0);
            cim = __builtin_amdgcn_mfma_f32_16x16x32_f16(AiL[1], bfr, cim, 0, 0, 0);
            // B2 scatter-store: amp a[0:4)=tt, a[4:8)=4q+r, a[8:12)=l15
            const int als = ((tt >> 1) & 3) ^ q;
            const int bes = q & 1;
            const int D = 4 * (l15 ^ (als << 2));
            #pragma unroll
            for (int r = 0; r < 4; ++r) {
                const int nu2 = tt + 16 * (4 * q + r);
                __half2 hp = __floats2half2_rn(cre[r], cim[r]);
                *(unsigned int*)(wbuf + 64 * (nu2 ^ bes) + D) = *(unsigned int*)&hp;
            }
        }
        { char* tmp = rbuf; rbuf = wbuf; wbuf = tmp; }

        // ================= pass G2 =================
        __syncthreads();
        #pragma unroll
        for (int T = 0; T < 4; ++T) {
            const int tt = wv * 4 + T;
            // B2 load: nu = l15 + 16*tt (lane split l15=a[0:4), tt=a[4:8))
            const int nu = l15 + 16 * tt;
            const int al = ((l15 >> 1) & 3) ^ ((tt >> 2) & 3);
            const int be = (tt >> 2) & 1;
            int4 raw = *(const int4*)(rbuf + 64 * (nu ^ be) + 16 * (q ^ al));
            half8 bfr; __builtin_memcpy(&bfr, &raw, 16);
            f32x4 cre = {0.f,0.f,0.f,0.f}, cim = {0.f,0.f,0.f,0.f};
            cre = __builtin_amdgcn_mfma_f32_16x16x32_f16(ArH[2], bfr, cre, 0, 0, 0);
            cre = __builtin_amdgcn_mfma_f32_16x16x32_f16(ArL[2], bfr, cre, 0, 0, 0);
            cim = __builtin_amdgcn_mfma_f32_16x16x32_f16(AiH[2], bfr, cim, 0, 0, 0);
            cim = __builtin_amdgcn_mfma_f32_16x16x32_f16(AiL[2], bfr, cim, 0, 0, 0);
            if (L < 2) {
                // B0 scatter-store via prefix parities: u[0:4)=l15, u[4:8)=tt, u[8:12)=4q+r
                const int taub = pfx4(tt);
                const int lowH = (piL ? 15 : 0) ^ taub;      // H0..H3
                const int s    = (lowH >> 3) & 1;            // pi ^ tau3
                const int als  = ((lowH >> 1) & 1) | ((((lowH >> 1) ^ (lowH >> 2)) & 1) << 1);
                const int bes  = q & 1;                      // H5^H6
                const int D = 4 * (Ml ^ (als << 2));
                #pragma unroll
                for (int r = 0; r < 4; ++r) {
                    const int rho = pfx4(4 * q + r);
                    const int H = lowH | (((s ? 15 : 0) ^ rho) << 4);
                    __half2 hp = __floats2half2_rn(cre[r], cim[r]);
                    *(unsigned int*)(wbuf + 64 * (H ^ bes) + D) = *(unsigned int*)&hp;
                }
            } else {
                // fold final CNOT + measurement (r15-verified); a = l15|tt<<4|(4q+r)<<8
                const int sT0 = T & 1, sT01 = (T ^ (T >> 1)) & 1;
                #pragma unroll
                for (int r = 0; r < 4; ++r) {
                    const float pr = cre[r] * cre[r] + cim[r] * cim[r];
                    A0 += pr;
                    AT0  += sT0 ? -pr : pr;
                    AT01 += sT01 ? -pr : pr;
                    AR0  += (sT01 ^ (r & 1)) ? -pr : pr;
                    AR01 += (sT01 ^ ((r ^ (r >> 1)) & 1)) ? -pr : pr;
                }
            }
        }
        { char* tmp = rbuf; rbuf = wbuf; wbuf = tmp; }
    }

    // ---- per-thread signed sums -> zp[12] (r15-verified)
    const int pl = __popc(l15) & 1;
    const int wv0 = wv & 1, wv1 = (wv >> 1) & 1, wv01 = wv0 ^ wv1;
    const int q0 = q & 1, q1 = (q >> 1) & 1;
    float zp[12];
    zp[1] = (__popc(l15 & 3) & 1) ? -A0 : A0;
    zp[2] = (__popc(l15 & 7) & 1) ? -A0 : A0;
    zp[3] = pl ? -A0 : A0;
    zp[4] = pl ? -AT0 : AT0;
    zp[5] = pl ? -AT01 : AT01;
    zp[6] = (pl ^ wv0) ? -AT01 : AT01;
    zp[7] = (pl ^ wv0 ^ wv1) ? -AT01 : AT01;
    zp[8] = (pl ^ wv01) ? -AR0 : AR0;
    zp[9] = (pl ^ wv01) ? -AR01 : AR01;
    zp[10] = (pl ^ wv01 ^ q0) ? -AR01 : AR01;
    zp[11] = (pl ^ wv01 ^ q0 ^ q1) ? -AR01 : AR01;
    zp[0]  = ((l15 & 1) ^ pl ^ wv01 ^ q0 ^ q1) ? -AR01 : AR01;

    #pragma unroll
    for (int i = 0; i < 12; ++i) {
        float vv = zp[i];
        #pragma unroll
        for (int off = 32; off > 0; off >>= 1)
            vv += __shfl_xor(vv, off, 64);
        zp[i] = vv;
    }

    // ---- epilogue (verified), aliasing LDS
    __syncthreads();
    float* stf  = (float*)lds;
    float* zred = stf;        // [4][12]
    float* qzs  = stf + 48;   // [12]
    float* hbuf = stf + 64;   // [64]

    if ((t & 63) == 0) {
        #pragma unroll
        for (int i = 0; i < 12; ++i) zred[wv * 12 + i] = zp[i];
    }
    __syncthreads();
    if (t < 12)
        qzs[t] = zred[t] + zred[12 + t] + zred[24 + t] + zred[36 + t];
    __syncthreads();

    if (t < 64) {
        float acc = b1[t];
        #pragma unroll
        for (int i = 0; i < 12; ++i) acc += qzs[i] * w1[t * 12 + i];
        hbuf[t] = fmaxf(acc, 0.0f);
    }
    __syncthreads();
    float acc = b2[t];
    #pragma unroll 4
    for (int k4 = 0; k4 < 16; ++k4) {
        const float4 wvv = ((const float4*)w2)[t * 16 + k4];
        acc += wvv.x * hbuf[k4 * 4 + 0] + wvv.y * hbuf[k4 * 4 + 1]
             + wvv.z * hbuf[k4 * 4 + 2] + wvv.w * hbuf[k4 * 4 + 3];
    }
    out[b * 256 + t] = acc;
}

extern "C" void kernel_launch(void* const* d_in, const int* in_sizes, int n_in,
                              void* d_out, int out_size, void* d_ws, size_t ws_size,
                              hipStream_t stream) {
    const float* x  = (const float*)d_in[0];
    const float* rw = (const float*)d_in[1];
    const float* rb = (const float*)d_in[2];
    const float* w1 = (const float*)d_in[3];
    const float* b1 = (const float*)d_in[4];
    const float* w2 = (const float*)d_in[5];
    const float* b2 = (const float*)d_in[6];
    float* out = (float*)d_out;
    float* uws = (float*)d_ws;                    // [B*96] floats = 786432 B

    const int batch = in_sizes[0] / 48;           // x is [B,48]
    const int total = batch * 12;
    qparam_kernel<<<(total + 255) / 256, 256, 0, stream>>>(x, rw, rb, uws, total);
    qreup_kernel<<<batch, 256, 0, stream>>>(uws, w1, b1, w2, b2, out);
}